// Round 11
// baseline (504.105 us; speedup 1.0000x reference)
//
#include <hip/hip_runtime.h>

// Problem constants
#define TT 16
#define NN 50000
#define FF 64
#define EE 131072
#define NEDGE (TT*EE)          // 2097152 = 8192*256 exactly
#define RPB 32                 // rows per range
#define NRANGE ((NN + RPB - 1) / RPB)   // 1563
#define NSUB 8                 // XCD-proxy sub-buckets per range
#define BCAP 256               // capacity per sub-bucket (mean 168, +6.8 sigma)
#define NBUCK (NRANGE*NSUB)    // 12504
#define SLOTS (NSUB*BCAP)      // 2048 int2 slots per range region
#define EMAX 1791              // sorted-edge capacity (slots before tail header)
#define TAILI (EMAX*2)         // int index of 513-int offset header in region

typedef __attribute__((ext_vector_type(8))) short bf16x8;
typedef __attribute__((ext_vector_type(4))) short bf16x4;
typedef __attribute__((ext_vector_type(4))) float f32x4;
typedef __attribute__((ext_vector_type(2))) int   i32x2;
typedef __attribute__((ext_vector_type(2))) unsigned u32x2;

// round-half-up f32->bf16 pair pack: 2 v_add + 1 v_perm. <=0.5 ulp, unbiased.
__device__ __forceinline__ unsigned pack2bf(float a, float b) {
    unsigned ua = __float_as_uint(a) + 0x8000u;
    unsigned ub = __float_as_uint(b) + 0x8000u;
    return __builtin_amdgcn_perm(ub, ua, 0x07060302u);
}
__device__ __forceinline__ float lo16f(unsigned u) { return __uint_as_float(u << 16); }
__device__ __forceinline__ float hi16f(unsigned u) { return __uint_as_float(u & 0xFFFF0000u); }

union U8 { unsigned u[4]; bf16x8 v; };
union U4 { unsigned u[2]; bf16x4 v; };

// K=16 bf16 MFMA. A: lane holds A[m=lane&15][k=(lane>>4)*4+j];
// B: B[k=(lane>>4)*4+j][n=lane&15]; C/D: row=(lane>>4)*4+reg, col=lane&15.
__device__ __forceinline__ f32x4 mfma16x16x16bf16(bf16x4 a, bf16x4 b, f32x4 c) {
#if __has_builtin(__builtin_amdgcn_mfma_f32_16x16x16bf16_1k)
    return __builtin_amdgcn_mfma_f32_16x16x16bf16_1k(a, b, c, 0, 0, 0);
#elif __has_builtin(__builtin_amdgcn_mfma_f32_16x16x16_bf16)
    return __builtin_amdgcn_mfma_f32_16x16x16_bf16(a, b, c, 0, 0, 0);
#else
    f32x4 d;
    asm volatile("v_mfma_f32_16x16x16_bf16 %0, %1, %2, %3\n\ts_nop 7\n\ts_nop 7"
                 : "=&v"(d) : "v"(a), "v"(b), "v"(c));
    return d;
#endif
}

// ---------------------------------------------------------------------------
// K1: Yt[node][k][fo] (node-major) = sum_s M[k,s] * sum_fi x[s][node][fi]*W[fi][fo]
// One wave per node, fully in-register; mix MFMA computes (M@P)^T -> packed 8B stores.
// x loads nontemporal (one-time stream; keep L3 for Yt).
// ---------------------------------------------------------------------------
__global__ __launch_bounds__(256) void k1_proj_mix(
    const float* __restrict__ x, const float* __restrict__ M,
    const float* __restrict__ W, unsigned short* __restrict__ Yt)
{
    const int tid  = threadIdx.x;
    const int wid  = tid >> 6;
    const int lane = tid & 63;
    const int col  = lane & 15;   // MFMA m/n index
    const int grp  = lane >> 4;   // MFMA k-group

    // W as B-frags for 16x16x32: lane holds B[k=q*32+grp*8+j][n=t*16+col]
    bf16x8 bw[2][4];
#pragma unroll
    for (int q = 0; q < 2; ++q)
#pragma unroll
        for (int t = 0; t < 4; ++t) {
            U8 w8;
#pragma unroll
            for (int p = 0; p < 4; ++p)
                w8.u[p] = pack2bf(W[(q*32 + grp*8 + 2*p)*FF + t*16 + col],
                                  W[(q*32 + grp*8 + 2*p + 1)*FF + t*16 + col]);
            bw[q][t] = w8.v;
        }

    // M fragment: element j = M[col][grp*4+j] (B-frag of mix MFMA = M^T)
    U4 m4;
    m4.u[0] = pack2bf(M[col*16 + grp*4 + 0], M[col*16 + grp*4 + 1]);
    m4.u[1] = pack2bf(M[col*16 + grp*4 + 2], M[col*16 + grp*4 + 3]);
    const bf16x4 mf = m4.v;

    const f32x4 zero = {0.f, 0.f, 0.f, 0.f};
    const int nwaves = gridDim.x * 4;

    for (int node = blockIdx.x*4 + wid; node < NN; node += nwaves) {
        // ---- load x rows direct to A-frags: lane reads row s=col, fi = q*32+grp*8+(0..7) ----
        const float* xb = x + (size_t)col*NN*FF + (size_t)node*FF + grp*8;
        f32x4 v0 = __builtin_nontemporal_load(reinterpret_cast<const f32x4*>(xb));
        f32x4 v1 = __builtin_nontemporal_load(reinterpret_cast<const f32x4*>(xb + 4));
        f32x4 v2 = __builtin_nontemporal_load(reinterpret_cast<const f32x4*>(xb + 32));
        f32x4 v3 = __builtin_nontemporal_load(reinterpret_cast<const f32x4*>(xb + 36));
        U8 a0, a1;
        a0.u[0] = pack2bf(v0[0], v0[1]); a0.u[1] = pack2bf(v0[2], v0[3]);
        a0.u[2] = pack2bf(v1[0], v1[1]); a0.u[3] = pack2bf(v1[2], v1[3]);
        a1.u[0] = pack2bf(v2[0], v2[1]); a1.u[1] = pack2bf(v2[2], v2[3]);
        a1.u[2] = pack2bf(v3[0], v3[1]); a1.u[3] = pack2bf(v3[2], v3[3]);

        // ---- P[s][fo] = X @ W via 16x16x32 MFMA (K=64 in 2 steps, 4 fo-tiles) ----
        f32x4 acc[4];
#pragma unroll
        for (int t = 0; t < 4; ++t) acc[t] = zero;
#pragma unroll
        for (int t = 0; t < 4; ++t)
            acc[t] = __builtin_amdgcn_mfma_f32_16x16x32_bf16(a0.v, bw[0][t], acc[t], 0, 0, 0);
#pragma unroll
        for (int t = 0; t < 4; ++t)
            acc[t] = __builtin_amdgcn_mfma_f32_16x16x32_bf16(a1.v, bw[1][t], acc[t], 0, 0, 0);

        // ---- Y^T = P^T @ M^T: lane holds Y[k=col][fo=t*16+grp*4+rr] -> packed 8B store
#pragma unroll
        for (int t = 0; t < 4; ++t) {
            U4 pb;
            pb.u[0] = pack2bf(acc[t][0], acc[t][1]);
            pb.u[1] = pack2bf(acc[t][2], acc[t][3]);
            f32x4 y = mfma16x16x16bf16(pb.v, mf, zero);
            u32x2 st;
            st[0] = pack2bf(y[0], y[1]);
            st[1] = pack2bf(y[2], y[3]);
            *reinterpret_cast<u32x2*>(Yt + (size_t)node*1024 + col*64 + t*16 + grp*4) = st;
        }
    }
}

// ---------------------------------------------------------------------------
// append: one thread per edge. Bucket = (row/32)*8 + (blockIdx&7) -> dense
// sequential writes per bucket, no write amplification.
// Entry: {col | key<<16, val}, key = (r&31)*16 + j.
// ---------------------------------------------------------------------------
__global__ __launch_bounds__(256) void append_kernel(
    const int* __restrict__ rows, const int* __restrict__ cols,
    const float* __restrict__ vals, int* __restrict__ bcnt,
    i32x2* __restrict__ btmp)
{
    const int i = blockIdx.x*256 + threadIdx.x;   // grid sized exactly NEDGE
    const int r = __builtin_nontemporal_load(rows + i);
    const int j = i >> 17;                        // EE = 2^17
    const int b = (r >> 5)*NSUB + (blockIdx.x & 7);
    const int pos = atomicAdd(&bcnt[b], 1);
    if (pos < BCAP) {
        i32x2 e;
        e[0] = __builtin_nontemporal_load(cols + i) | (((r & 31)*16 + j) << 16);
        e[1] = __float_as_int(__builtin_nontemporal_load(vals + i));
        btmp[(size_t)b*BCAP + pos] = e;
    }
}

// ---------------------------------------------------------------------------
// sort: block per range. Counting-sort the range's edges in LDS, write back
// IN PLACE (linear, coalesced), sorted by key=(rl,j), + 513-int offset header.
// ---------------------------------------------------------------------------
__global__ __launch_bounds__(256) void sort_kernel(
    const int* __restrict__ bcnt, i32x2* __restrict__ btmp)
{
    __shared__ i32x2 sbuf[SLOTS];     // 16KB
    __shared__ int scnt[512], soff[512], scur[512], pscan[256];

    const int tid = threadIdx.x;
    const int blk = blockIdx.x;
    i32x2* region = btmp + (size_t)blk*SLOTS;

    scnt[tid] = 0; scnt[tid + 256] = 0;
    __syncthreads();

    int bc[NSUB]; i32x2 ent[NSUB];
#pragma unroll
    for (int s = 0; s < NSUB; ++s) {
        int c = bcnt[blk*NSUB + s];
        bc[s] = c < BCAP ? c : BCAP;
    }
#pragma unroll
    for (int s = 0; s < NSUB; ++s)
        if (tid < bc[s]) {
            ent[s] = region[s*BCAP + tid];
            atomicAdd(&scnt[((unsigned)ent[s][0]) >> 16], 1);
        }
    __syncthreads();

    const int a0 = scnt[2*tid], a1 = scnt[2*tid + 1];
    const int ps = a0 + a1;
    pscan[tid] = ps;
    __syncthreads();
    for (int o = 1; o < 256; o <<= 1) {
        int v = (tid >= o) ? pscan[tid - o] : 0;
        __syncthreads();
        pscan[tid] += v;
        __syncthreads();
    }
    const int excl = pscan[tid] - ps;
    soff[2*tid] = excl;      soff[2*tid + 1] = excl + a0;
    scur[2*tid] = excl;      scur[2*tid + 1] = excl + a0;
    __syncthreads();

#pragma unroll
    for (int s = 0; s < NSUB; ++s)
        if (tid < bc[s]) {
            const int key = ((unsigned)ent[s][0]) >> 16;
            const int pos = atomicAdd(&scur[key], 1);
            i32x2 se; se[0] = ent[s][0] & 0xFFFF; se[1] = ent[s][1];
            sbuf[pos] = se;
        }
    __syncthreads();

    const int total = soff[511] + scnt[511];
    const int lim = total < EMAX ? total : EMAX;
    for (int i = tid; i < lim; i += 256) region[i] = sbuf[i];
    int* tail = (int*)region + TAILI;
    tail[tid] = soff[tid];
    tail[tid + 256] = soff[tid + 256];
    if (tid == 0) tail[512] = lim;
}

// ---------------------------------------------------------------------------
// k2_gather: TWO waves per row, split by k-range (k0-7 / k8-15).
// Slice sets disjoint -> no duplicate Yt traffic, no cross-wave reduction,
// no syncthreads. acc = 8 x f32x4 = 32 VGPR; launch_bounds(256,8) pins
// VGPR <= 64 -> 32-waves/CU class. out stores are PLAIN (r10: nt-stores
// scalarized -> 3.5x write amplification, 711MB for a 205MB output).
// ---------------------------------------------------------------------------
template<int J, int KLO, int KHI>
__device__ __forceinline__ void k2_batch(int p0, int nj, int sbase, int esub, int fq,
    const i32x2* eb, const unsigned short* __restrict__ Yt,
    const float* __restrict__ M, f32x4* acc)
{
    const int p = p0 + esub;
    const bool act = p < nj;
    const int li = act ? (sbase + p) : 0;
    const i32x2 ent = eb[li];                 // LDS read
    const float v = act ? __int_as_float(ent[1]) : 0.f;
    const int node = act ? ent[0] : 0;        // masked lanes read Yt[0]
    const unsigned short* yb = Yt + (size_t)node*1024 + fq*4;
#pragma unroll
    for (int d = 0; d < 3; ++d) {
        if (J + d >= KLO && J + d <= KHI && J + d < 16) {
            const u32x2 uv = *reinterpret_cast<const u32x2*>(yb + (J + d)*64);
            const float wv = M[(J + d)*16 + J] * v;
            acc[J + d - KLO][0] = fmaf(wv, lo16f(uv[0]), acc[J + d - KLO][0]);
            acc[J + d - KLO][1] = fmaf(wv, hi16f(uv[0]), acc[J + d - KLO][1]);
            acc[J + d - KLO][2] = fmaf(wv, lo16f(uv[1]), acc[J + d - KLO][2]);
            acc[J + d - KLO][3] = fmaf(wv, hi16f(uv[1]), acc[J + d - KLO][3]);
        }
    }
}

__global__ __launch_bounds__(256, 8) void k2_gather(
    const unsigned short* __restrict__ Yt, const float* __restrict__ M,
    const i32x2* __restrict__ btmp, float* __restrict__ out)
{
    __shared__ i32x2 ebuf[4][96];
    const int tid  = threadIdx.x;
    const int wid  = tid >> 6;
    const int lane = tid & 63;
    const int esub = lane >> 4;   // edge slot 0..3
    const int fq   = lane & 15;   // feature quad
    const int rown = wid >> 1;
    const int half = wid & 1;     // 0: k0-7 (j0-7), 1: k8-15 (j6-15)
    const int r   = blockIdx.x*2 + rown;   // 25000*2 = 50000 exact
    const int blk = r >> 5;
    const int rl  = r & 31;

    const i32x2* region = btmp + (size_t)blk*SLOTS;
    const int* tail = (const int*)region + TAILI;
    int o_l = 0;
    if (lane < 17) o_l = __builtin_nontemporal_load(tail + rl*16 + lane);
    int off[17];
#pragma unroll
    for (int j = 0; j < 17; ++j) off[j] = __builtin_amdgcn_readlane(o_l, j);

    const int jlo = half ? 6 : 0;
    const int jhi = half ? 15 : 7;
    int ntot = off[jhi + 1] - off[jlo];
    ntot = ntot < 96 ? ntot : 96;
    const i32x2* rowsrc = region + off[jlo];

    i32x2* eb = ebuf[wid];
    if (lane < ntot)      eb[lane]      = __builtin_nontemporal_load(rowsrc + lane);
    if (lane + 64 < ntot) eb[lane + 64] = __builtin_nontemporal_load(rowsrc + lane + 64);

    int c[16], sb[16];
#pragma unroll
    for (int j = 0; j < 16; ++j) {
        c[j]  = off[j+1] - off[j];
        sb[j] = off[j] - off[jlo];
    }

    f32x4 acc[8];
#pragma unroll
    for (int k = 0; k < 8; ++k) acc[k] = (f32x4){0.f, 0.f, 0.f, 0.f};

    if (half == 0) {
        // sections j0..7, keep slices k<=7
#define P1(J) k2_batch<J,0,7>(0, c[J], sb[J], esub, fq, eb, Yt, M, acc);
        P1(0) P1(1) P1(2) P1(3) P1(4) P1(5) P1(6) P1(7)
#undef P1
#define P2(J) for (int p0 = 4; p0 < c[J]; p0 += 4) \
            k2_batch<J,0,7>(p0, c[J], sb[J], esub, fq, eb, Yt, M, acc);
        P2(0) P2(1) P2(2) P2(3) P2(4) P2(5) P2(6) P2(7)
#undef P2
    } else {
        // sections j6..15, keep slices k>=8
#define P1(J) k2_batch<J,8,15>(0, c[J], sb[J], esub, fq, eb, Yt, M, acc);
        P1(6) P1(7) P1(8) P1(9) P1(10) P1(11) P1(12) P1(13) P1(14) P1(15)
#undef P1
#define P2(J) for (int p0 = 4; p0 < c[J]; p0 += 4) \
            k2_batch<J,8,15>(p0, c[J], sb[J], esub, fq, eb, Yt, M, acc);
        P2(6) P2(7) P2(8) P2(9) P2(10) P2(11) P2(12) P2(13) P2(14) P2(15)
#undef P2
    }

#pragma unroll
    for (int k = 0; k < 8; ++k) {
#pragma unroll
        for (int u = 0; u < 4; ++u) {
            acc[k][u] += __shfl_xor(acc[k][u], 16);
            acc[k][u] += __shfl_xor(acc[k][u], 32);
        }
    }
    if (esub == 0) {
        const int kbase = half*8;
#pragma unroll
        for (int k = 0; k < 8; ++k) {
            *reinterpret_cast<f32x4*>(out + ((size_t)(kbase + k)*NN + r)*FF + fq*4) = acc[k];
        }
    }
}

// ---------------------------------------------------------------------------
extern "C" void kernel_launch(void* const* d_in, const int* in_sizes, int n_in,
                              void* d_out, int out_size, void* d_ws, size_t ws_size,
                              hipStream_t stream) {
    (void)in_sizes; (void)n_in; (void)out_size; (void)ws_size;
    const float* x     = (const float*)d_in[0];
    const float* M     = (const float*)d_in[1];
    const float* avals = (const float*)d_in[2];
    const float* W     = (const float*)d_in[3];
    const int*   arows = (const int*)d_in[4];
    const int*   acols = (const int*)d_in[5];
    float* out = (float*)d_out;

    // workspace carve (~128.1 MB total)
    char* ws = (char*)d_ws;
    size_t o = 0;
    unsigned short* Yt = (unsigned short*)(ws + o); o += (size_t)TT*NN*FF*2;  // 102.4 MB
    o = (o + 255) & ~(size_t)255;
    int* bcnt = (int*)(ws + o); o += (size_t)NBUCK*4;  o = (o + 255) & ~(size_t)255;
    i32x2* btmp = (i32x2*)(ws + o);                    // 12504*2048*8 = 25.6 MB

    (void)hipMemsetAsync(bcnt, 0, (size_t)NBUCK*4, stream);
    hipLaunchKernelGGL(k1_proj_mix, dim3(2048), dim3(256), 0, stream, x, M, W, Yt);
    hipLaunchKernelGGL(append_kernel, dim3(NEDGE/256), dim3(256), 0, stream,
                       arows, acols, avals, bcnt, btmp);
    hipLaunchKernelGGL(sort_kernel, dim3(NRANGE), dim3(256), 0, stream, bcnt, btmp);
    hipLaunchKernelGGL(k2_gather, dim3(25000), dim3(256), 0, stream, Yt, M, btmp, out);
}

// Round 12
// 360.863 us; speedup vs baseline: 1.3969x; 1.3969x over previous
//
#include <hip/hip_runtime.h>

// Problem constants
#define TT 16
#define NN 50000
#define FF 64
#define EE 131072
#define NEDGE (TT*EE)          // 2097152 = 8192*256 exactly
#define RPB 32                 // rows per range
#define NRANGE ((NN + RPB - 1) / RPB)   // 1563
#define NSUB 8                 // XCD-proxy sub-buckets per range
#define BCAP 256               // capacity per sub-bucket (mean 168, +6.8 sigma)
#define NBUCK (NRANGE*NSUB)    // 12504
#define SLOTS (NSUB*BCAP)      // 2048 int2 slots per range region
#define EMAX 1791              // sorted-edge capacity (slots before tail header)
#define TAILI (EMAX*2)         // int index of 513-int offset header in region

typedef __attribute__((ext_vector_type(8))) short bf16x8;
typedef __attribute__((ext_vector_type(4))) short bf16x4;
typedef __attribute__((ext_vector_type(4))) float f32x4;
typedef __attribute__((ext_vector_type(2))) int   i32x2;
typedef __attribute__((ext_vector_type(2))) unsigned u32x2;

// round-half-up f32->bf16 pair pack: 2 v_add + 1 v_perm. <=0.5 ulp, unbiased.
__device__ __forceinline__ unsigned pack2bf(float a, float b) {
    unsigned ua = __float_as_uint(a) + 0x8000u;
    unsigned ub = __float_as_uint(b) + 0x8000u;
    return __builtin_amdgcn_perm(ub, ua, 0x07060302u);
}
__device__ __forceinline__ float lo16f(unsigned u) { return __uint_as_float(u << 16); }
__device__ __forceinline__ float hi16f(unsigned u) { return __uint_as_float(u & 0xFFFF0000u); }

union U8 { unsigned u[4]; bf16x8 v; };
union U4 { unsigned u[2]; bf16x4 v; };

// K=16 bf16 MFMA. A: lane holds A[m=lane&15][k=(lane>>4)*4+j];
// B: B[k=(lane>>4)*4+j][n=lane&15]; C/D: row=(lane>>4)*4+reg, col=lane&15.
__device__ __forceinline__ f32x4 mfma16x16x16bf16(bf16x4 a, bf16x4 b, f32x4 c) {
#if __has_builtin(__builtin_amdgcn_mfma_f32_16x16x16bf16_1k)
    return __builtin_amdgcn_mfma_f32_16x16x16bf16_1k(a, b, c, 0, 0, 0);
#elif __has_builtin(__builtin_amdgcn_mfma_f32_16x16x16_bf16)
    return __builtin_amdgcn_mfma_f32_16x16x16_bf16(a, b, c, 0, 0, 0);
#else
    f32x4 d;
    asm volatile("v_mfma_f32_16x16x16_bf16 %0, %1, %2, %3\n\ts_nop 7\n\ts_nop 7"
                 : "=&v"(d) : "v"(a), "v"(b), "v"(c));
    return d;
#endif
}

// ---------------------------------------------------------------------------
// K1: Yt[node][k][fo] (node-major) = sum_s M[k,s] * sum_fi x[s][node][fi]*W[fi][fo]
// One wave per node-pair (2-node unroll: both nodes' 8 x-loads issue before
// any pack/MFMA -> 2x MLP on the scattered x reads). Mix MFMA computes
// (M@P)^T -> packed 8B stores. x loads nontemporal (read-once stream).
// ---------------------------------------------------------------------------
__global__ __launch_bounds__(256) void k1_proj_mix(
    const float* __restrict__ x, const float* __restrict__ M,
    const float* __restrict__ W, unsigned short* __restrict__ Yt)
{
    const int tid  = threadIdx.x;
    const int wid  = tid >> 6;
    const int lane = tid & 63;
    const int col  = lane & 15;   // MFMA m/n index
    const int grp  = lane >> 4;   // MFMA k-group

    // W as B-frags for 16x16x32: lane holds B[k=q*32+grp*8+j][n=t*16+col]
    bf16x8 bw[2][4];
#pragma unroll
    for (int q = 0; q < 2; ++q)
#pragma unroll
        for (int t = 0; t < 4; ++t) {
            U8 w8;
#pragma unroll
            for (int p = 0; p < 4; ++p)
                w8.u[p] = pack2bf(W[(q*32 + grp*8 + 2*p)*FF + t*16 + col],
                                  W[(q*32 + grp*8 + 2*p + 1)*FF + t*16 + col]);
            bw[q][t] = w8.v;
        }

    // M fragment: element j = M[col][grp*4+j] (B-frag of mix MFMA = M^T)
    U4 m4;
    m4.u[0] = pack2bf(M[col*16 + grp*4 + 0], M[col*16 + grp*4 + 1]);
    m4.u[1] = pack2bf(M[col*16 + grp*4 + 2], M[col*16 + grp*4 + 3]);
    const bf16x4 mf = m4.v;

    const f32x4 zero = {0.f, 0.f, 0.f, 0.f};
    const int nwaves = gridDim.x * 4;
    const size_t lane_off = (size_t)col*NN*FF + grp*8;

    for (int node = blockIdx.x*4 + wid; node < NN; node += 2*nwaves) {
        const int nodeB = node + nwaves;
        const bool hasB = nodeB < NN;

        // ---- issue ALL x loads first (A: 4, B: 4) for MLP ----
        const float* xa = x + lane_off + (size_t)node*FF;
        f32x4 va0 = __builtin_nontemporal_load(reinterpret_cast<const f32x4*>(xa));
        f32x4 va1 = __builtin_nontemporal_load(reinterpret_cast<const f32x4*>(xa + 4));
        f32x4 va2 = __builtin_nontemporal_load(reinterpret_cast<const f32x4*>(xa + 32));
        f32x4 va3 = __builtin_nontemporal_load(reinterpret_cast<const f32x4*>(xa + 36));
        const float* xb = x + lane_off + (size_t)(hasB ? nodeB : node)*FF;
        f32x4 vb0 = __builtin_nontemporal_load(reinterpret_cast<const f32x4*>(xb));
        f32x4 vb1 = __builtin_nontemporal_load(reinterpret_cast<const f32x4*>(xb + 4));
        f32x4 vb2 = __builtin_nontemporal_load(reinterpret_cast<const f32x4*>(xb + 32));
        f32x4 vb3 = __builtin_nontemporal_load(reinterpret_cast<const f32x4*>(xb + 36));

        // ---- node A: pack, proj MFMA, mix MFMA, store ----
        {
            U8 a0, a1;
            a0.u[0] = pack2bf(va0[0], va0[1]); a0.u[1] = pack2bf(va0[2], va0[3]);
            a0.u[2] = pack2bf(va1[0], va1[1]); a0.u[3] = pack2bf(va1[2], va1[3]);
            a1.u[0] = pack2bf(va2[0], va2[1]); a1.u[1] = pack2bf(va2[2], va2[3]);
            a1.u[2] = pack2bf(va3[0], va3[1]); a1.u[3] = pack2bf(va3[2], va3[3]);
            f32x4 acc[4];
#pragma unroll
            for (int t = 0; t < 4; ++t) acc[t] = zero;
#pragma unroll
            for (int t = 0; t < 4; ++t)
                acc[t] = __builtin_amdgcn_mfma_f32_16x16x32_bf16(a0.v, bw[0][t], acc[t], 0, 0, 0);
#pragma unroll
            for (int t = 0; t < 4; ++t)
                acc[t] = __builtin_amdgcn_mfma_f32_16x16x32_bf16(a1.v, bw[1][t], acc[t], 0, 0, 0);
#pragma unroll
            for (int t = 0; t < 4; ++t) {
                U4 pb;
                pb.u[0] = pack2bf(acc[t][0], acc[t][1]);
                pb.u[1] = pack2bf(acc[t][2], acc[t][3]);
                f32x4 y = mfma16x16x16bf16(pb.v, mf, zero);
                u32x2 st;
                st[0] = pack2bf(y[0], y[1]);
                st[1] = pack2bf(y[2], y[3]);
                *reinterpret_cast<u32x2*>(Yt + (size_t)node*1024 + col*64 + t*16 + grp*4) = st;
            }
        }
        // ---- node B ----
        if (hasB) {
            U8 a0, a1;
            a0.u[0] = pack2bf(vb0[0], vb0[1]); a0.u[1] = pack2bf(vb0[2], vb0[3]);
            a0.u[2] = pack2bf(vb1[0], vb1[1]); a0.u[3] = pack2bf(vb1[2], vb1[3]);
            a1.u[0] = pack2bf(vb2[0], vb2[1]); a1.u[1] = pack2bf(vb2[2], vb2[3]);
            a1.u[2] = pack2bf(vb3[0], vb3[1]); a1.u[3] = pack2bf(vb3[2], vb3[3]);
            f32x4 acc[4];
#pragma unroll
            for (int t = 0; t < 4; ++t) acc[t] = zero;
#pragma unroll
            for (int t = 0; t < 4; ++t)
                acc[t] = __builtin_amdgcn_mfma_f32_16x16x32_bf16(a0.v, bw[0][t], acc[t], 0, 0, 0);
#pragma unroll
            for (int t = 0; t < 4; ++t)
                acc[t] = __builtin_amdgcn_mfma_f32_16x16x32_bf16(a1.v, bw[1][t], acc[t], 0, 0, 0);
#pragma unroll
            for (int t = 0; t < 4; ++t) {
                U4 pb;
                pb.u[0] = pack2bf(acc[t][0], acc[t][1]);
                pb.u[1] = pack2bf(acc[t][2], acc[t][3]);
                f32x4 y = mfma16x16x16bf16(pb.v, mf, zero);
                u32x2 st;
                st[0] = pack2bf(y[0], y[1]);
                st[1] = pack2bf(y[2], y[3]);
                *reinterpret_cast<u32x2*>(Yt + (size_t)nodeB*1024 + col*64 + t*16 + grp*4) = st;
            }
        }
    }
}

// ---------------------------------------------------------------------------
// append: one thread per edge. Bucket = (row/32)*8 + (blockIdx&7) -> dense
// sequential writes per bucket, no write amplification.
// Entry: {col | key<<16, val}, key = (r&31)*16 + j.
// ---------------------------------------------------------------------------
__global__ __launch_bounds__(256) void append_kernel(
    const int* __restrict__ rows, const int* __restrict__ cols,
    const float* __restrict__ vals, int* __restrict__ bcnt,
    i32x2* __restrict__ btmp)
{
    const int i = blockIdx.x*256 + threadIdx.x;   // grid sized exactly NEDGE
    const int r = __builtin_nontemporal_load(rows + i);
    const int j = i >> 17;                        // EE = 2^17
    const int b = (r >> 5)*NSUB + (blockIdx.x & 7);
    const int pos = atomicAdd(&bcnt[b], 1);
    if (pos < BCAP) {
        i32x2 e;
        e[0] = __builtin_nontemporal_load(cols + i) | (((r & 31)*16 + j) << 16);
        e[1] = __float_as_int(__builtin_nontemporal_load(vals + i));
        btmp[(size_t)b*BCAP + pos] = e;
    }
}

// ---------------------------------------------------------------------------
// sort: block per range. Counting-sort the range's edges in LDS, write back
// IN PLACE (linear, coalesced), sorted by key=(rl,j), + 513-int offset header.
// ---------------------------------------------------------------------------
__global__ __launch_bounds__(256) void sort_kernel(
    const int* __restrict__ bcnt, i32x2* __restrict__ btmp)
{
    __shared__ i32x2 sbuf[SLOTS];     // 16KB
    __shared__ int scnt[512], soff[512], scur[512], pscan[256];

    const int tid = threadIdx.x;
    const int blk = blockIdx.x;
    i32x2* region = btmp + (size_t)blk*SLOTS;

    scnt[tid] = 0; scnt[tid + 256] = 0;
    __syncthreads();

    int bc[NSUB]; i32x2 ent[NSUB];
#pragma unroll
    for (int s = 0; s < NSUB; ++s) {
        int c = bcnt[blk*NSUB + s];
        bc[s] = c < BCAP ? c : BCAP;
    }
#pragma unroll
    for (int s = 0; s < NSUB; ++s)
        if (tid < bc[s]) {
            ent[s] = region[s*BCAP + tid];
            atomicAdd(&scnt[((unsigned)ent[s][0]) >> 16], 1);
        }
    __syncthreads();

    const int a0 = scnt[2*tid], a1 = scnt[2*tid + 1];
    const int ps = a0 + a1;
    pscan[tid] = ps;
    __syncthreads();
    for (int o = 1; o < 256; o <<= 1) {
        int v = (tid >= o) ? pscan[tid - o] : 0;
        __syncthreads();
        pscan[tid] += v;
        __syncthreads();
    }
    const int excl = pscan[tid] - ps;
    soff[2*tid] = excl;      soff[2*tid + 1] = excl + a0;
    scur[2*tid] = excl;      scur[2*tid + 1] = excl + a0;
    __syncthreads();

#pragma unroll
    for (int s = 0; s < NSUB; ++s)
        if (tid < bc[s]) {
            const int key = ((unsigned)ent[s][0]) >> 16;
            const int pos = atomicAdd(&scur[key], 1);
            i32x2 se; se[0] = ent[s][0] & 0xFFFF; se[1] = ent[s][1];
            sbuf[pos] = se;
        }
    __syncthreads();

    const int total = soff[511] + scnt[511];
    const int lim = total < EMAX ? total : EMAX;
    for (int i = tid; i < lim; i += 256) region[i] = sbuf[i];
    int* tail = (int*)region + TAILI;
    tail[tid] = soff[tid];
    tail[tid + 256] = soff[tid + 256];
    if (tid == 0) tail[512] = lim;
}

// ---------------------------------------------------------------------------
// k2_gather: EXACT round-7 structure (proven 166us): one wave per row,
// acc[16], plain loads, grid 12500. r10/r11 showed: k-split to 2 waves/row +
// occupancy 72% INFLATED HBM FETCH 368->578MB (L3 thrash on the Yt gather
// stream) and slowed k2 2x. Cache effectiveness, not occupancy, binds here.
// ---------------------------------------------------------------------------
template<int J>
__device__ __forceinline__ void k2_batch(int p0, int nj, int sbase, int esub, int fq,
    const i32x2* eb, const unsigned short* __restrict__ Yt,
    const float* __restrict__ M, f32x4* acc)
{
    const int p = p0 + esub;
    const bool act = p < nj;
    const int li = act ? (sbase + p) : 0;
    const i32x2 ent = eb[li];                 // LDS read
    const float v = act ? __int_as_float(ent[1]) : 0.f;
    const int node = act ? ent[0] : 0;        // masked lanes read Yt[0]
    const unsigned short* yb = Yt + (size_t)node*1024 + J*64 + fq*4;
    {
        const u32x2 uv = *reinterpret_cast<const u32x2*>(yb);
        const float wv = M[J*17] * v;
        acc[J][0] = fmaf(wv, lo16f(uv[0]), acc[J][0]);
        acc[J][1] = fmaf(wv, hi16f(uv[0]), acc[J][1]);
        acc[J][2] = fmaf(wv, lo16f(uv[1]), acc[J][2]);
        acc[J][3] = fmaf(wv, hi16f(uv[1]), acc[J][3]);
    }
    if constexpr (J < 15) {
        const u32x2 uv = *reinterpret_cast<const u32x2*>(yb + 64);
        const float wv = M[J*17 + 16] * v;
        acc[J+1][0] = fmaf(wv, lo16f(uv[0]), acc[J+1][0]);
        acc[J+1][1] = fmaf(wv, hi16f(uv[0]), acc[J+1][1]);
        acc[J+1][2] = fmaf(wv, lo16f(uv[1]), acc[J+1][2]);
        acc[J+1][3] = fmaf(wv, hi16f(uv[1]), acc[J+1][3]);
    }
    if constexpr (J < 14) {
        const u32x2 uv = *reinterpret_cast<const u32x2*>(yb + 128);
        const float wv = M[J*17 + 32] * v;
        acc[J+2][0] = fmaf(wv, lo16f(uv[0]), acc[J+2][0]);
        acc[J+2][1] = fmaf(wv, hi16f(uv[0]), acc[J+2][1]);
        acc[J+2][2] = fmaf(wv, lo16f(uv[1]), acc[J+2][2]);
        acc[J+2][3] = fmaf(wv, hi16f(uv[1]), acc[J+2][3]);
    }
}

__global__ __launch_bounds__(256) void k2_gather(
    const unsigned short* __restrict__ Yt, const float* __restrict__ M,
    const i32x2* __restrict__ btmp, float* __restrict__ out)
{
    __shared__ i32x2 ebuf[4][128];
    const int tid  = threadIdx.x;
    const int wid  = tid >> 6;
    const int lane = tid & 63;
    const int esub = lane >> 4;   // edge slot 0..3
    const int fq   = lane & 15;   // feature quad
    const int r   = blockIdx.x*4 + wid;   // 12500*4 = 50000 exact
    const int blk = r >> 5;
    const int rl  = r & 31;

    const i32x2* region = btmp + (size_t)blk*SLOTS;
    const int* tail = (const int*)region + TAILI;
    int o_l = 0;
    if (lane < 17) o_l = tail[rl*16 + lane];
    int off[17];
#pragma unroll
    for (int j = 0; j < 17; ++j) off[j] = __builtin_amdgcn_readlane(o_l, j);
    int ntot = off[16] - off[0];
    ntot = ntot < 128 ? ntot : 128;
    const i32x2* rowsrc = region + off[0];

    i32x2* eb = ebuf[wid];
    if (lane < ntot)      eb[lane]      = rowsrc[lane];
    if (lane + 64 < ntot) eb[lane + 64] = rowsrc[lane + 64];

    int c[16], sb[16];
#pragma unroll
    for (int j = 0; j < 16; ++j) {
        c[j]  = off[j+1] - off[j];
        sb[j] = off[j] - off[0];
    }

    f32x4 acc[16];
#pragma unroll
    for (int k = 0; k < 16; ++k) acc[k] = (f32x4){0.f, 0.f, 0.f, 0.f};

    // pass 1: first batch of every section, straight-line
#define P1(J) k2_batch<J>(0, c[J], sb[J], esub, fq, eb, Yt, M, acc);
    P1(0)  P1(1)  P1(2)  P1(3)  P1(4)  P1(5)  P1(6)  P1(7)
    P1(8)  P1(9)  P1(10) P1(11) P1(12) P1(13) P1(14) P1(15)
#undef P1
    // pass 2: residual batches (usually empty)
#define P2(J) for (int p0 = 4; p0 < c[J]; p0 += 4) \
        k2_batch<J>(p0, c[J], sb[J], esub, fq, eb, Yt, M, acc);
    P2(0)  P2(1)  P2(2)  P2(3)  P2(4)  P2(5)  P2(6)  P2(7)
    P2(8)  P2(9)  P2(10) P2(11) P2(12) P2(13) P2(14) P2(15)
#undef P2

#pragma unroll
    for (int k = 0; k < 16; ++k) {
#pragma unroll
        for (int u = 0; u < 4; ++u) {
            acc[k][u] += __shfl_xor(acc[k][u], 16);
            acc[k][u] += __shfl_xor(acc[k][u], 32);
        }
    }
    if (esub == 0) {
#pragma unroll
        for (int k = 0; k < 16; ++k) {
            *reinterpret_cast<f32x4*>(out + ((size_t)k*NN + r)*FF + fq*4) = acc[k];
        }
    }
}

// ---------------------------------------------------------------------------
extern "C" void kernel_launch(void* const* d_in, const int* in_sizes, int n_in,
                              void* d_out, int out_size, void* d_ws, size_t ws_size,
                              hipStream_t stream) {
    (void)in_sizes; (void)n_in; (void)out_size; (void)ws_size;
    const float* x     = (const float*)d_in[0];
    const float* M     = (const float*)d_in[1];
    const float* avals = (const float*)d_in[2];
    const float* W     = (const float*)d_in[3];
    const int*   arows = (const int*)d_in[4];
    const int*   acols = (const int*)d_in[5];
    float* out = (float*)d_out;

    // workspace carve (~128.1 MB total)
    char* ws = (char*)d_ws;
    size_t o = 0;
    unsigned short* Yt = (unsigned short*)(ws + o); o += (size_t)TT*NN*FF*2;  // 102.4 MB
    o = (o + 255) & ~(size_t)255;
    int* bcnt = (int*)(ws + o); o += (size_t)NBUCK*4;  o = (o + 255) & ~(size_t)255;
    i32x2* btmp = (i32x2*)(ws + o);                    // 12504*2048*8 = 25.6 MB

    (void)hipMemsetAsync(bcnt, 0, (size_t)NBUCK*4, stream);
    hipLaunchKernelGGL(k1_proj_mix, dim3(2048), dim3(256), 0, stream, x, M, W, Yt);
    hipLaunchKernelGGL(append_kernel, dim3(NEDGE/256), dim3(256), 0, stream,
                       arows, acols, avals, bcnt, btmp);
    hipLaunchKernelGGL(sort_kernel, dim3(NRANGE), dim3(256), 0, stream, bcnt, btmp);
    hipLaunchKernelGGL(k2_gather, dim3(12500), dim3(256), 0, stream, Yt, M, btmp, out);
}

// Round 13
// 349.750 us; speedup vs baseline: 1.4413x; 1.0318x over previous
//
#include <hip/hip_runtime.h>

// Problem constants
#define TT 16
#define NN 50000
#define FF 64
#define EE 131072
#define NEDGE (TT*EE)          // 2097152 = 8192*256 exactly
#define RPB 32                 // rows per range
#define NRANGE ((NN + RPB - 1) / RPB)   // 1563
#define NSUB 8                 // XCD-proxy sub-buckets per range
#define BCAP 256               // capacity per sub-bucket (mean 168, +6.8 sigma)
#define NBUCK (NRANGE*NSUB)    // 12504
#define SLOTS (NSUB*BCAP)      // 2048 int2 slots per range region
#define EMAX 1791              // sorted-edge capacity (slots before tail header)
#define TAILI (EMAX*2)         // int index of 513-int offset header in region
#define K1BLKS 6250            // k1 blocks in fused dispatch (4 waves x 2 nodes)
#define APPBLKS (NEDGE/256)    // 8192 append blocks

typedef __attribute__((ext_vector_type(8))) short bf16x8;
typedef __attribute__((ext_vector_type(4))) short bf16x4;
typedef __attribute__((ext_vector_type(4))) float f32x4;
typedef __attribute__((ext_vector_type(2))) int   i32x2;
typedef __attribute__((ext_vector_type(2))) unsigned u32x2;

// round-half-up f32->bf16 pair pack: 2 v_add + 1 v_perm. <=0.5 ulp, unbiased.
__device__ __forceinline__ unsigned pack2bf(float a, float b) {
    unsigned ua = __float_as_uint(a) + 0x8000u;
    unsigned ub = __float_as_uint(b) + 0x8000u;
    return __builtin_amdgcn_perm(ub, ua, 0x07060302u);
}
__device__ __forceinline__ float lo16f(unsigned u) { return __uint_as_float(u << 16); }
__device__ __forceinline__ float hi16f(unsigned u) { return __uint_as_float(u & 0xFFFF0000u); }

union U8 { unsigned u[4]; bf16x8 v; };
union U4 { unsigned u[2]; bf16x4 v; };

// K=16 bf16 MFMA. A: lane holds A[m=lane&15][k=(lane>>4)*4+j];
// B: B[k=(lane>>4)*4+j][n=lane&15]; C/D: row=(lane>>4)*4+reg, col=lane&15.
__device__ __forceinline__ f32x4 mfma16x16x16bf16(bf16x4 a, bf16x4 b, f32x4 c) {
#if __has_builtin(__builtin_amdgcn_mfma_f32_16x16x16bf16_1k)
    return __builtin_amdgcn_mfma_f32_16x16x16bf16_1k(a, b, c, 0, 0, 0);
#elif __has_builtin(__builtin_amdgcn_mfma_f32_16x16x16_bf16)
    return __builtin_amdgcn_mfma_f32_16x16x16_bf16(a, b, c, 0, 0, 0);
#else
    f32x4 d;
    asm volatile("v_mfma_f32_16x16x16_bf16 %0, %1, %2, %3\n\ts_nop 7\n\ts_nop 7"
                 : "=&v"(d) : "v"(a), "v"(b), "v"(c));
    return d;
#endif
}

// ---------------------------------------------------------------------------
// Fused dispatch: blocks [0,K1BLKS) run k1 (proj+mix, 2 consecutive nodes per
// wave, no loop -> short blocks), blocks [K1BLKS, K1BLKS+APPBLKS) run append.
// k1 and append are data-independent; fusing overlaps append's atomic/latency
// stream under k1's BW stream (serial pipeline cost ~30us -> ~0).
// ---------------------------------------------------------------------------
__global__ __launch_bounds__(256) void k1_append(
    const float* __restrict__ x, const float* __restrict__ M,
    const float* __restrict__ W, unsigned short* __restrict__ Yt,
    const int* __restrict__ rows, const int* __restrict__ cols,
    const float* __restrict__ vals, int* __restrict__ bcnt,
    i32x2* __restrict__ btmp)
{
    if (blockIdx.x < K1BLKS) {
        // ================= k1: proj + mix =================
        const int tid  = threadIdx.x;
        const int wid  = tid >> 6;
        const int lane = tid & 63;
        const int col  = lane & 15;   // MFMA m/n index
        const int grp  = lane >> 4;   // MFMA k-group

        // W as B-frags for 16x16x32: lane holds B[k=q*32+grp*8+j][n=t*16+col]
        bf16x8 bw[2][4];
#pragma unroll
        for (int q = 0; q < 2; ++q)
#pragma unroll
            for (int t = 0; t < 4; ++t) {
                U8 w8;
#pragma unroll
                for (int p = 0; p < 4; ++p)
                    w8.u[p] = pack2bf(W[(q*32 + grp*8 + 2*p)*FF + t*16 + col],
                                      W[(q*32 + grp*8 + 2*p + 1)*FF + t*16 + col]);
                bw[q][t] = w8.v;
            }

        // M fragment: element j = M[col][grp*4+j] (B-frag of mix MFMA = M^T)
        U4 m4;
        m4.u[0] = pack2bf(M[col*16 + grp*4 + 0], M[col*16 + grp*4 + 1]);
        m4.u[1] = pack2bf(M[col*16 + grp*4 + 2], M[col*16 + grp*4 + 3]);
        const bf16x4 mf = m4.v;

        const f32x4 zero = {0.f, 0.f, 0.f, 0.f};
        const int node = (blockIdx.x*4 + wid)*2;     // 6250*4*2 = 50000 exact
        const size_t lane_off = (size_t)col*NN*FF + grp*8;

        // ---- issue ALL x loads first (nodes node, node+1; 512B/slice contiguous) ----
        const float* xa = x + lane_off + (size_t)node*FF;
        f32x4 va0 = __builtin_nontemporal_load(reinterpret_cast<const f32x4*>(xa));
        f32x4 va1 = __builtin_nontemporal_load(reinterpret_cast<const f32x4*>(xa + 4));
        f32x4 va2 = __builtin_nontemporal_load(reinterpret_cast<const f32x4*>(xa + 32));
        f32x4 va3 = __builtin_nontemporal_load(reinterpret_cast<const f32x4*>(xa + 36));
        f32x4 vb0 = __builtin_nontemporal_load(reinterpret_cast<const f32x4*>(xa + 64));
        f32x4 vb1 = __builtin_nontemporal_load(reinterpret_cast<const f32x4*>(xa + 68));
        f32x4 vb2 = __builtin_nontemporal_load(reinterpret_cast<const f32x4*>(xa + 96));
        f32x4 vb3 = __builtin_nontemporal_load(reinterpret_cast<const f32x4*>(xa + 100));

#pragma unroll
        for (int n2 = 0; n2 < 2; ++n2) {
            U8 a0, a1;
            if (n2 == 0) {
                a0.u[0] = pack2bf(va0[0], va0[1]); a0.u[1] = pack2bf(va0[2], va0[3]);
                a0.u[2] = pack2bf(va1[0], va1[1]); a0.u[3] = pack2bf(va1[2], va1[3]);
                a1.u[0] = pack2bf(va2[0], va2[1]); a1.u[1] = pack2bf(va2[2], va2[3]);
                a1.u[2] = pack2bf(va3[0], va3[1]); a1.u[3] = pack2bf(va3[2], va3[3]);
            } else {
                a0.u[0] = pack2bf(vb0[0], vb0[1]); a0.u[1] = pack2bf(vb0[2], vb0[3]);
                a0.u[2] = pack2bf(vb1[0], vb1[1]); a0.u[3] = pack2bf(vb1[2], vb1[3]);
                a1.u[0] = pack2bf(vb2[0], vb2[1]); a1.u[1] = pack2bf(vb2[2], vb2[3]);
                a1.u[2] = pack2bf(vb3[0], vb3[1]); a1.u[3] = pack2bf(vb3[2], vb3[3]);
            }
            f32x4 acc[4];
#pragma unroll
            for (int t = 0; t < 4; ++t) acc[t] = zero;
#pragma unroll
            for (int t = 0; t < 4; ++t)
                acc[t] = __builtin_amdgcn_mfma_f32_16x16x32_bf16(a0.v, bw[0][t], acc[t], 0, 0, 0);
#pragma unroll
            for (int t = 0; t < 4; ++t)
                acc[t] = __builtin_amdgcn_mfma_f32_16x16x32_bf16(a1.v, bw[1][t], acc[t], 0, 0, 0);
#pragma unroll
            for (int t = 0; t < 4; ++t) {
                U4 pb;
                pb.u[0] = pack2bf(acc[t][0], acc[t][1]);
                pb.u[1] = pack2bf(acc[t][2], acc[t][3]);
                f32x4 y = mfma16x16x16bf16(pb.v, mf, zero);
                u32x2 st;
                st[0] = pack2bf(y[0], y[1]);
                st[1] = pack2bf(y[2], y[3]);
                *reinterpret_cast<u32x2*>(Yt + (size_t)(node + n2)*1024 + col*64 + t*16 + grp*4) = st;
            }
        }
    } else {
        // ================= append =================
        const int i = (blockIdx.x - K1BLKS)*256 + threadIdx.x;   // 0..NEDGE-1
        const int r = __builtin_nontemporal_load(rows + i);
        const int j = i >> 17;                        // EE = 2^17
        const int b = (r >> 5)*NSUB + (blockIdx.x & 7);
        const int pos = atomicAdd(&bcnt[b], 1);
        if (pos < BCAP) {
            i32x2 e;
            e[0] = __builtin_nontemporal_load(cols + i) | (((r & 31)*16 + j) << 16);
            e[1] = __float_as_int(__builtin_nontemporal_load(vals + i));
            btmp[(size_t)b*BCAP + pos] = e;
        }
    }
}

// ---------------------------------------------------------------------------
// sort: block per range. Counting-sort the range's edges in LDS, write back
// IN PLACE (linear, coalesced), sorted by key=(rl,j), + 513-int offset header.
// ---------------------------------------------------------------------------
__global__ __launch_bounds__(256) void sort_kernel(
    const int* __restrict__ bcnt, i32x2* __restrict__ btmp)
{
    __shared__ i32x2 sbuf[SLOTS];     // 16KB
    __shared__ int scnt[512], soff[512], scur[512], pscan[256];

    const int tid = threadIdx.x;
    const int blk = blockIdx.x;
    i32x2* region = btmp + (size_t)blk*SLOTS;

    scnt[tid] = 0; scnt[tid + 256] = 0;
    __syncthreads();

    int bc[NSUB]; i32x2 ent[NSUB];
#pragma unroll
    for (int s = 0; s < NSUB; ++s) {
        int c = bcnt[blk*NSUB + s];
        bc[s] = c < BCAP ? c : BCAP;
    }
#pragma unroll
    for (int s = 0; s < NSUB; ++s)
        if (tid < bc[s]) {
            ent[s] = region[s*BCAP + tid];
            atomicAdd(&scnt[((unsigned)ent[s][0]) >> 16], 1);
        }
    __syncthreads();

    const int a0 = scnt[2*tid], a1 = scnt[2*tid + 1];
    const int ps = a0 + a1;
    pscan[tid] = ps;
    __syncthreads();
    for (int o = 1; o < 256; o <<= 1) {
        int v = (tid >= o) ? pscan[tid - o] : 0;
        __syncthreads();
        pscan[tid] += v;
        __syncthreads();
    }
    const int excl = pscan[tid] - ps;
    soff[2*tid] = excl;      soff[2*tid + 1] = excl + a0;
    scur[2*tid] = excl;      scur[2*tid + 1] = excl + a0;
    __syncthreads();

#pragma unroll
    for (int s = 0; s < NSUB; ++s)
        if (tid < bc[s]) {
            const int key = ((unsigned)ent[s][0]) >> 16;
            const int pos = atomicAdd(&scur[key], 1);
            i32x2 se; se[0] = ent[s][0] & 0xFFFF; se[1] = ent[s][1];
            sbuf[pos] = se;
        }
    __syncthreads();

    const int total = soff[511] + scnt[511];
    const int lim = total < EMAX ? total : EMAX;
    for (int i = tid; i < lim; i += 256) region[i] = sbuf[i];
    int* tail = (int*)region + TAILI;
    tail[tid] = soff[tid];
    tail[tid + 256] = soff[tid + 256];
    if (tid == 0) tail[512] = lim;
}

// ---------------------------------------------------------------------------
// k2_gather: one wave per row (r12 proven ~154us). acc[16], plain loads.
// Cache effectiveness (L3 on the Yt gather stream), not occupancy, binds here
// (r10/r11 evidence). Unchanged.
// ---------------------------------------------------------------------------
template<int J>
__device__ __forceinline__ void k2_batch(int p0, int nj, int sbase, int esub, int fq,
    const i32x2* eb, const unsigned short* __restrict__ Yt,
    const float* __restrict__ M, f32x4* acc)
{
    const int p = p0 + esub;
    const bool act = p < nj;
    const int li = act ? (sbase + p) : 0;
    const i32x2 ent = eb[li];                 // LDS read
    const float v = act ? __int_as_float(ent[1]) : 0.f;
    const int node = act ? ent[0] : 0;        // masked lanes read Yt[0]
    const unsigned short* yb = Yt + (size_t)node*1024 + J*64 + fq*4;
    {
        const u32x2 uv = *reinterpret_cast<const u32x2*>(yb);
        const float wv = M[J*17] * v;
        acc[J][0] = fmaf(wv, lo16f(uv[0]), acc[J][0]);
        acc[J][1] = fmaf(wv, hi16f(uv[0]), acc[J][1]);
        acc[J][2] = fmaf(wv, lo16f(uv[1]), acc[J][2]);
        acc[J][3] = fmaf(wv, hi16f(uv[1]), acc[J][3]);
    }
    if constexpr (J < 15) {
        const u32x2 uv = *reinterpret_cast<const u32x2*>(yb + 64);
        const float wv = M[J*17 + 16] * v;
        acc[J+1][0] = fmaf(wv, lo16f(uv[0]), acc[J+1][0]);
        acc[J+1][1] = fmaf(wv, hi16f(uv[0]), acc[J+1][1]);
        acc[J+1][2] = fmaf(wv, lo16f(uv[1]), acc[J+1][2]);
        acc[J+1][3] = fmaf(wv, hi16f(uv[1]), acc[J+1][3]);
    }
    if constexpr (J < 14) {
        const u32x2 uv = *reinterpret_cast<const u32x2*>(yb + 128);
        const float wv = M[J*17 + 32] * v;
        acc[J+2][0] = fmaf(wv, lo16f(uv[0]), acc[J+2][0]);
        acc[J+2][1] = fmaf(wv, hi16f(uv[0]), acc[J+2][1]);
        acc[J+2][2] = fmaf(wv, lo16f(uv[1]), acc[J+2][2]);
        acc[J+2][3] = fmaf(wv, hi16f(uv[1]), acc[J+2][3]);
    }
}

__global__ __launch_bounds__(256) void k2_gather(
    const unsigned short* __restrict__ Yt, const float* __restrict__ M,
    const i32x2* __restrict__ btmp, float* __restrict__ out)
{
    __shared__ i32x2 ebuf[4][128];
    const int tid  = threadIdx.x;
    const int wid  = tid >> 6;
    const int lane = tid & 63;
    const int esub = lane >> 4;   // edge slot 0..3
    const int fq   = lane & 15;   // feature quad
    const int r   = blockIdx.x*4 + wid;   // 12500*4 = 50000 exact
    const int blk = r >> 5;
    const int rl  = r & 31;

    const i32x2* region = btmp + (size_t)blk*SLOTS;
    const int* tail = (const int*)region + TAILI;
    int o_l = 0;
    if (lane < 17) o_l = tail[rl*16 + lane];
    int off[17];
#pragma unroll
    for (int j = 0; j < 17; ++j) off[j] = __builtin_amdgcn_readlane(o_l, j);
    int ntot = off[16] - off[0];
    ntot = ntot < 128 ? ntot : 128;
    const i32x2* rowsrc = region + off[0];

    i32x2* eb = ebuf[wid];
    if (lane < ntot)      eb[lane]      = rowsrc[lane];
    if (lane + 64 < ntot) eb[lane + 64] = rowsrc[lane + 64];

    int c[16], sb[16];
#pragma unroll
    for (int j = 0; j < 16; ++j) {
        c[j]  = off[j+1] - off[j];
        sb[j] = off[j] - off[0];
    }

    f32x4 acc[16];
#pragma unroll
    for (int k = 0; k < 16; ++k) acc[k] = (f32x4){0.f, 0.f, 0.f, 0.f};

    // pass 1: first batch of every section, straight-line
#define P1(J) k2_batch<J>(0, c[J], sb[J], esub, fq, eb, Yt, M, acc);
    P1(0)  P1(1)  P1(2)  P1(3)  P1(4)  P1(5)  P1(6)  P1(7)
    P1(8)  P1(9)  P1(10) P1(11) P1(12) P1(13) P1(14) P1(15)
#undef P1
    // pass 2: residual batches (usually empty)
#define P2(J) for (int p0 = 4; p0 < c[J]; p0 += 4) \
        k2_batch<J>(p0, c[J], sb[J], esub, fq, eb, Yt, M, acc);
    P2(0)  P2(1)  P2(2)  P2(3)  P2(4)  P2(5)  P2(6)  P2(7)
    P2(8)  P2(9)  P2(10) P2(11) P2(12) P2(13) P2(14) P2(15)
#undef P2

#pragma unroll
    for (int k = 0; k < 16; ++k) {
#pragma unroll
        for (int u = 0; u < 4; ++u) {
            acc[k][u] += __shfl_xor(acc[k][u], 16);
            acc[k][u] += __shfl_xor(acc[k][u], 32);
        }
    }
    if (esub == 0) {
#pragma unroll
        for (int k = 0; k < 16; ++k) {
            *reinterpret_cast<f32x4*>(out + ((size_t)k*NN + r)*FF + fq*4) = acc[k];
        }
    }
}

// ---------------------------------------------------------------------------
extern "C" void kernel_launch(void* const* d_in, const int* in_sizes, int n_in,
                              void* d_out, int out_size, void* d_ws, size_t ws_size,
                              hipStream_t stream) {
    (void)in_sizes; (void)n_in; (void)out_size; (void)ws_size;
    const float* x     = (const float*)d_in[0];
    const float* M     = (const float*)d_in[1];
    const float* avals = (const float*)d_in[2];
    const float* W     = (const float*)d_in[3];
    const int*   arows = (const int*)d_in[4];
    const int*   acols = (const int*)d_in[5];
    float* out = (float*)d_out;

    // workspace carve (~128.1 MB total)
    char* ws = (char*)d_ws;
    size_t o = 0;
    unsigned short* Yt = (unsigned short*)(ws + o); o += (size_t)TT*NN*FF*2;  // 102.4 MB
    o = (o + 255) & ~(size_t)255;
    int* bcnt = (int*)(ws + o); o += (size_t)NBUCK*4;  o = (o + 255) & ~(size_t)255;
    i32x2* btmp = (i32x2*)(ws + o);                    // 12504*2048*8 = 25.6 MB

    (void)hipMemsetAsync(bcnt, 0, (size_t)NBUCK*4, stream);
    hipLaunchKernelGGL(k1_append, dim3(K1BLKS + APPBLKS), dim3(256), 0, stream,
                       x, M, W, Yt, arows, acols, avals, bcnt, btmp);
    hipLaunchKernelGGL(sort_kernel, dim3(NRANGE), dim3(256), 0, stream, bcnt, btmp);
    hipLaunchKernelGGL(k2_gather, dim3(12500), dim3(256), 0, stream, Yt, M, btmp, out);
}

// Round 14
// 340.294 us; speedup vs baseline: 1.4814x; 1.0278x over previous
//
#include <hip/hip_runtime.h>

// Problem constants
#define TT 16
#define NN 50000
#define FF 64
#define EE 131072
#define NEDGE (TT*EE)          // 2097152 = 8192*256 exactly
#define RPB 32                 // rows per range
#define NRANGE ((NN + RPB - 1) / RPB)   // 1563
#define NSUB 8                 // XCD-proxy sub-buckets per range
#define BCAP 256               // capacity per sub-bucket (mean 168, +6.8 sigma)
#define NBUCK (NRANGE*NSUB)    // 12504
#define SLOTS (NSUB*BCAP)      // 2048 int2 slots per range region
#define EMAX 1791              // sorted-edge capacity (slots before tail header)
#define TAILI (EMAX*2)         // int index of 513-int offset header in region
#define K1BLKS 1563            // k1 blocks (4 waves x 8 nodes = 32 nodes/block)
#define APPBLKS (NEDGE/256)    // 8192 append blocks

typedef __attribute__((ext_vector_type(8))) short bf16x8;
typedef __attribute__((ext_vector_type(4))) short bf16x4;
typedef __attribute__((ext_vector_type(4))) float f32x4;
typedef __attribute__((ext_vector_type(2))) int   i32x2;
typedef __attribute__((ext_vector_type(2))) unsigned u32x2;

// round-half-up f32->bf16 pair pack: 2 v_add + 1 v_perm. <=0.5 ulp, unbiased.
__device__ __forceinline__ unsigned pack2bf(float a, float b) {
    unsigned ua = __float_as_uint(a) + 0x8000u;
    unsigned ub = __float_as_uint(b) + 0x8000u;
    return __builtin_amdgcn_perm(ub, ua, 0x07060302u);
}
__device__ __forceinline__ float lo16f(unsigned u) { return __uint_as_float(u << 16); }
__device__ __forceinline__ float hi16f(unsigned u) { return __uint_as_float(u & 0xFFFF0000u); }

union U8 { unsigned u[4]; bf16x8 v; };
union U4 { unsigned u[2]; bf16x4 v; };

// K=16 bf16 MFMA. A: lane holds A[m=lane&15][k=(lane>>4)*4+j];
// B: B[k=(lane>>4)*4+j][n=lane&15]; C/D: row=(lane>>4)*4+reg, col=lane&15.
__device__ __forceinline__ f32x4 mfma16x16x16bf16(bf16x4 a, bf16x4 b, f32x4 c) {
#if __has_builtin(__builtin_amdgcn_mfma_f32_16x16x16bf16_1k)
    return __builtin_amdgcn_mfma_f32_16x16x16bf16_1k(a, b, c, 0, 0, 0);
#elif __has_builtin(__builtin_amdgcn_mfma_f32_16x16x16_bf16)
    return __builtin_amdgcn_mfma_f32_16x16x16_bf16(a, b, c, 0, 0, 0);
#else
    f32x4 d;
    asm volatile("v_mfma_f32_16x16x16_bf16 %0, %1, %2, %3\n\ts_nop 7\n\ts_nop 7"
                 : "=&v"(d) : "v"(a), "v"(b), "v"(c));
    return d;
#endif
}

// ---------------------------------------------------------------------------
// Fused dispatch: blocks [0,K1BLKS) run k1 (proj+mix, 8 nodes per wave in a
// 4x unrolled pair-loop -> W/M setup amortized 4x vs r13's 2-node version,
// whose 8% VALUBusy showed setup latency dominating), blocks [K1BLKS, ...)
// run append. All k1 blocks (~6/CU) are resident immediately; append's 8192
// blocks stream through concurrently.
// ---------------------------------------------------------------------------
__global__ __launch_bounds__(256) void k1_append(
    const float* __restrict__ x, const float* __restrict__ M,
    const float* __restrict__ W, unsigned short* __restrict__ Yt,
    const int* __restrict__ rows, const int* __restrict__ cols,
    const float* __restrict__ vals, int* __restrict__ bcnt,
    i32x2* __restrict__ btmp)
{
    if (blockIdx.x < K1BLKS) {
        // ================= k1: proj + mix =================
        const int tid  = threadIdx.x;
        const int wid  = tid >> 6;
        const int lane = tid & 63;
        const int col  = lane & 15;   // MFMA m/n index
        const int grp  = lane >> 4;   // MFMA k-group

        // W as B-frags for 16x16x32: lane holds B[k=q*32+grp*8+j][n=t*16+col]
        bf16x8 bw[2][4];
#pragma unroll
        for (int q = 0; q < 2; ++q)
#pragma unroll
            for (int t = 0; t < 4; ++t) {
                U8 w8;
#pragma unroll
                for (int p = 0; p < 4; ++p)
                    w8.u[p] = pack2bf(W[(q*32 + grp*8 + 2*p)*FF + t*16 + col],
                                      W[(q*32 + grp*8 + 2*p + 1)*FF + t*16 + col]);
                bw[q][t] = w8.v;
            }

        // M fragment: element j = M[col][grp*4+j] (B-frag of mix MFMA = M^T)
        U4 m4;
        m4.u[0] = pack2bf(M[col*16 + grp*4 + 0], M[col*16 + grp*4 + 1]);
        m4.u[1] = pack2bf(M[col*16 + grp*4 + 2], M[col*16 + grp*4 + 3]);
        const bf16x4 mf = m4.v;

        const f32x4 zero = {0.f, 0.f, 0.f, 0.f};
        const int wave_id = blockIdx.x*4 + wid;      // 6252 waves x 8 nodes
        const size_t lane_off = (size_t)col*NN*FF + grp*8;

#pragma unroll
        for (int it = 0; it < 4; ++it) {
            const int node = wave_id*8 + it*2;
            if (node < NN) {
                // ---- issue the pair's 8 x loads first ----
                const float* xa = x + lane_off + (size_t)node*FF;
                f32x4 va0 = __builtin_nontemporal_load(reinterpret_cast<const f32x4*>(xa));
                f32x4 va1 = __builtin_nontemporal_load(reinterpret_cast<const f32x4*>(xa + 4));
                f32x4 va2 = __builtin_nontemporal_load(reinterpret_cast<const f32x4*>(xa + 32));
                f32x4 va3 = __builtin_nontemporal_load(reinterpret_cast<const f32x4*>(xa + 36));
                f32x4 vb0 = __builtin_nontemporal_load(reinterpret_cast<const f32x4*>(xa + 64));
                f32x4 vb1 = __builtin_nontemporal_load(reinterpret_cast<const f32x4*>(xa + 68));
                f32x4 vb2 = __builtin_nontemporal_load(reinterpret_cast<const f32x4*>(xa + 96));
                f32x4 vb3 = __builtin_nontemporal_load(reinterpret_cast<const f32x4*>(xa + 100));

#pragma unroll
                for (int n2 = 0; n2 < 2; ++n2) {
                    U8 a0, a1;
                    if (n2 == 0) {
                        a0.u[0] = pack2bf(va0[0], va0[1]); a0.u[1] = pack2bf(va0[2], va0[3]);
                        a0.u[2] = pack2bf(va1[0], va1[1]); a0.u[3] = pack2bf(va1[2], va1[3]);
                        a1.u[0] = pack2bf(va2[0], va2[1]); a1.u[1] = pack2bf(va2[2], va2[3]);
                        a1.u[2] = pack2bf(va3[0], va3[1]); a1.u[3] = pack2bf(va3[2], va3[3]);
                    } else {
                        a0.u[0] = pack2bf(vb0[0], vb0[1]); a0.u[1] = pack2bf(vb0[2], vb0[3]);
                        a0.u[2] = pack2bf(vb1[0], vb1[1]); a0.u[3] = pack2bf(vb1[2], vb1[3]);
                        a1.u[0] = pack2bf(vb2[0], vb2[1]); a1.u[1] = pack2bf(vb2[2], vb2[3]);
                        a1.u[2] = pack2bf(vb3[0], vb3[1]); a1.u[3] = pack2bf(vb3[2], vb3[3]);
                    }
                    f32x4 acc[4];
#pragma unroll
                    for (int t = 0; t < 4; ++t) acc[t] = zero;
#pragma unroll
                    for (int t = 0; t < 4; ++t)
                        acc[t] = __builtin_amdgcn_mfma_f32_16x16x32_bf16(a0.v, bw[0][t], acc[t], 0, 0, 0);
#pragma unroll
                    for (int t = 0; t < 4; ++t)
                        acc[t] = __builtin_amdgcn_mfma_f32_16x16x32_bf16(a1.v, bw[1][t], acc[t], 0, 0, 0);
#pragma unroll
                    for (int t = 0; t < 4; ++t) {
                        U4 pb;
                        pb.u[0] = pack2bf(acc[t][0], acc[t][1]);
                        pb.u[1] = pack2bf(acc[t][2], acc[t][3]);
                        f32x4 y = mfma16x16x16bf16(pb.v, mf, zero);
                        u32x2 st;
                        st[0] = pack2bf(y[0], y[1]);
                        st[1] = pack2bf(y[2], y[3]);
                        *reinterpret_cast<u32x2*>(Yt + (size_t)(node + n2)*1024 + col*64 + t*16 + grp*4) = st;
                    }
                }
            }
        }
    } else {
        // ================= append =================
        const int i = (blockIdx.x - K1BLKS)*256 + threadIdx.x;   // 0..NEDGE-1
        const int r = __builtin_nontemporal_load(rows + i);
        const int j = i >> 17;                        // EE = 2^17
        const int b = (r >> 5)*NSUB + (blockIdx.x & 7);
        const int pos = atomicAdd(&bcnt[b], 1);
        if (pos < BCAP) {
            i32x2 e;
            e[0] = __builtin_nontemporal_load(cols + i) | (((r & 31)*16 + j) << 16);
            e[1] = __float_as_int(__builtin_nontemporal_load(vals + i));
            btmp[(size_t)b*BCAP + pos] = e;
        }
    }
}

// ---------------------------------------------------------------------------
// sort: block per range. Counting-sort the range's edges in LDS, write back
// IN PLACE (linear, coalesced), sorted by key=(rl,j), + 513-int offset header.
// ---------------------------------------------------------------------------
__global__ __launch_bounds__(256) void sort_kernel(
    const int* __restrict__ bcnt, i32x2* __restrict__ btmp)
{
    __shared__ i32x2 sbuf[SLOTS];     // 16KB
    __shared__ int scnt[512], soff[512], scur[512], pscan[256];

    const int tid = threadIdx.x;
    const int blk = blockIdx.x;
    i32x2* region = btmp + (size_t)blk*SLOTS;

    scnt[tid] = 0; scnt[tid + 256] = 0;
    __syncthreads();

    int bc[NSUB]; i32x2 ent[NSUB];
#pragma unroll
    for (int s = 0; s < NSUB; ++s) {
        int c = bcnt[blk*NSUB + s];
        bc[s] = c < BCAP ? c : BCAP;
    }
#pragma unroll
    for (int s = 0; s < NSUB; ++s)
        if (tid < bc[s]) {
            ent[s] = region[s*BCAP + tid];
            atomicAdd(&scnt[((unsigned)ent[s][0]) >> 16], 1);
        }
    __syncthreads();

    const int a0 = scnt[2*tid], a1 = scnt[2*tid + 1];
    const int ps = a0 + a1;
    pscan[tid] = ps;
    __syncthreads();
    for (int o = 1; o < 256; o <<= 1) {
        int v = (tid >= o) ? pscan[tid - o] : 0;
        __syncthreads();
        pscan[tid] += v;
        __syncthreads();
    }
    const int excl = pscan[tid] - ps;
    soff[2*tid] = excl;      soff[2*tid + 1] = excl + a0;
    scur[2*tid] = excl;      scur[2*tid + 1] = excl + a0;
    __syncthreads();

#pragma unroll
    for (int s = 0; s < NSUB; ++s)
        if (tid < bc[s]) {
            const int key = ((unsigned)ent[s][0]) >> 16;
            const int pos = atomicAdd(&scur[key], 1);
            i32x2 se; se[0] = ent[s][0] & 0xFFFF; se[1] = ent[s][1];
            sbuf[pos] = se;
        }
    __syncthreads();

    const int total = soff[511] + scnt[511];
    const int lim = total < EMAX ? total : EMAX;
    for (int i = tid; i < lim; i += 256) region[i] = sbuf[i];
    int* tail = (int*)region + TAILI;
    tail[tid] = soff[tid];
    tail[tid + 256] = soff[tid + 256];
    if (tid == 0) tail[512] = lim;
}

// ---------------------------------------------------------------------------
// k2_gather: one wave per row (proven ~154us). acc[16], plain loads.
// Cache effectiveness (L3 on the Yt gather stream), not occupancy, binds here
// (r10/r11 evidence). Unchanged.
// ---------------------------------------------------------------------------
template<int J>
__device__ __forceinline__ void k2_batch(int p0, int nj, int sbase, int esub, int fq,
    const i32x2* eb, const unsigned short* __restrict__ Yt,
    const float* __restrict__ M, f32x4* acc)
{
    const int p = p0 + esub;
    const bool act = p < nj;
    const int li = act ? (sbase + p) : 0;
    const i32x2 ent = eb[li];                 // LDS read
    const float v = act ? __int_as_float(ent[1]) : 0.f;
    const int node = act ? ent[0] : 0;        // masked lanes read Yt[0]
    const unsigned short* yb = Yt + (size_t)node*1024 + J*64 + fq*4;
    {
        const u32x2 uv = *reinterpret_cast<const u32x2*>(yb);
        const float wv = M[J*17] * v;
        acc[J][0] = fmaf(wv, lo16f(uv[0]), acc[J][0]);
        acc[J][1] = fmaf(wv, hi16f(uv[0]), acc[J][1]);
        acc[J][2] = fmaf(wv, lo16f(uv[1]), acc[J][2]);
        acc[J][3] = fmaf(wv, hi16f(uv[1]), acc[J][3]);
    }
    if constexpr (J < 15) {
        const u32x2 uv = *reinterpret_cast<const u32x2*>(yb + 64);
        const float wv = M[J*17 + 16] * v;
        acc[J+1][0] = fmaf(wv, lo16f(uv[0]), acc[J+1][0]);
        acc[J+1][1] = fmaf(wv, hi16f(uv[0]), acc[J+1][1]);
        acc[J+1][2] = fmaf(wv, lo16f(uv[1]), acc[J+1][2]);
        acc[J+1][3] = fmaf(wv, hi16f(uv[1]), acc[J+1][3]);
    }
    if constexpr (J < 14) {
        const u32x2 uv = *reinterpret_cast<const u32x2*>(yb + 128);
        const float wv = M[J*17 + 32] * v;
        acc[J+2][0] = fmaf(wv, lo16f(uv[0]), acc[J+2][0]);
        acc[J+2][1] = fmaf(wv, hi16f(uv[0]), acc[J+2][1]);
        acc[J+2][2] = fmaf(wv, lo16f(uv[1]), acc[J+2][2]);
        acc[J+2][3] = fmaf(wv, hi16f(uv[1]), acc[J+2][3]);
    }
}

__global__ __launch_bounds__(256) void k2_gather(
    const unsigned short* __restrict__ Yt, const float* __restrict__ M,
    const i32x2* __restrict__ btmp, float* __restrict__ out)
{
    __shared__ i32x2 ebuf[4][128];
    const int tid  = threadIdx.x;
    const int wid  = tid >> 6;
    const int lane = tid & 63;
    const int esub = lane >> 4;   // edge slot 0..3
    const int fq   = lane & 15;   // feature quad
    const int r   = blockIdx.x*4 + wid;   // 12500*4 = 50000 exact
    const int blk = r >> 5;
    const int rl  = r & 31;

    const i32x2* region = btmp + (size_t)blk*SLOTS;
    const int* tail = (const int*)region + TAILI;
    int o_l = 0;
    if (lane < 17) o_l = tail[rl*16 + lane];
    int off[17];
#pragma unroll
    for (int j = 0; j < 17; ++j) off[j] = __builtin_amdgcn_readlane(o_l, j);
    int ntot = off[16] - off[0];
    ntot = ntot < 128 ? ntot : 128;
    const i32x2* rowsrc = region + off[0];

    i32x2* eb = ebuf[wid];
    if (lane < ntot)      eb[lane]      = rowsrc[lane];
    if (lane + 64 < ntot) eb[lane + 64] = rowsrc[lane + 64];

    int c[16], sb[16];
#pragma unroll
    for (int j = 0; j < 16; ++j) {
        c[j]  = off[j+1] - off[j];
        sb[j] = off[j] - off[0];
    }

    f32x4 acc[16];
#pragma unroll
    for (int k = 0; k < 16; ++k) acc[k] = (f32x4){0.f, 0.f, 0.f, 0.f};

    // pass 1: first batch of every section, straight-line
#define P1(J) k2_batch<J>(0, c[J], sb[J], esub, fq, eb, Yt, M, acc);
    P1(0)  P1(1)  P1(2)  P1(3)  P1(4)  P1(5)  P1(6)  P1(7)
    P1(8)  P1(9)  P1(10) P1(11) P1(12) P1(13) P1(14) P1(15)
#undef P1
    // pass 2: residual batches (usually empty)
#define P2(J) for (int p0 = 4; p0 < c[J]; p0 += 4) \
        k2_batch<J>(p0, c[J], sb[J], esub, fq, eb, Yt, M, acc);
    P2(0)  P2(1)  P2(2)  P2(3)  P2(4)  P2(5)  P2(6)  P2(7)
    P2(8)  P2(9)  P2(10) P2(11) P2(12) P2(13) P2(14) P2(15)
#undef P2

#pragma unroll
    for (int k = 0; k < 16; ++k) {
#pragma unroll
        for (int u = 0; u < 4; ++u) {
            acc[k][u] += __shfl_xor(acc[k][u], 16);
            acc[k][u] += __shfl_xor(acc[k][u], 32);
        }
    }
    if (esub == 0) {
#pragma unroll
        for (int k = 0; k < 16; ++k) {
            *reinterpret_cast<f32x4*>(out + ((size_t)k*NN + r)*FF + fq*4) = acc[k];
        }
    }
}

// ---------------------------------------------------------------------------
extern "C" void kernel_launch(void* const* d_in, const int* in_sizes, int n_in,
                              void* d_out, int out_size, void* d_ws, size_t ws_size,
                              hipStream_t stream) {
    (void)in_sizes; (void)n_in; (void)out_size; (void)ws_size;
    const float* x     = (const float*)d_in[0];
    const float* M     = (const float*)d_in[1];
    const float* avals = (const float*)d_in[2];
    const float* W     = (const float*)d_in[3];
    const int*   arows = (const int*)d_in[4];
    const int*   acols = (const int*)d_in[5];
    float* out = (float*)d_out;

    // workspace carve (~128.1 MB total)
    char* ws = (char*)d_ws;
    size_t o = 0;
    unsigned short* Yt = (unsigned short*)(ws + o); o += (size_t)TT*NN*FF*2;  // 102.4 MB
    o = (o + 255) & ~(size_t)255;
    int* bcnt = (int*)(ws + o); o += (size_t)NBUCK*4;  o = (o + 255) & ~(size_t)255;
    i32x2* btmp = (i32x2*)(ws + o);                    // 12504*2048*8 = 25.6 MB

    (void)hipMemsetAsync(bcnt, 0, (size_t)NBUCK*4, stream);
    hipLaunchKernelGGL(k1_append, dim3(K1BLKS + APPBLKS), dim3(256), 0, stream,
                       x, M, W, Yt, arows, acols, avals, bcnt, btmp);
    hipLaunchKernelGGL(sort_kernel, dim3(NRANGE), dim3(256), 0, stream, bcnt, btmp);
    hipLaunchKernelGGL(k2_gather, dim3(12500), dim3(256), 0, stream, Yt, M, btmp, out);
}

// Round 15
// 328.877 us; speedup vs baseline: 1.5328x; 1.0347x over previous
//
#include <hip/hip_runtime.h>

// Problem constants
#define TT 16
#define NN 50000
#define FF 64
#define EE 131072
#define NEDGE (TT*EE)          // 2097152 = 8192*256 exactly
#define RPB 32                 // rows per range
#define NRANGE ((NN + RPB - 1) / RPB)   // 1563
#define NSUB 8                 // XCD-proxy sub-buckets per range
#define BCAP 256               // capacity per sub-bucket (mean 168, +6.8 sigma)
#define NBUCK (NRANGE*NSUB)    // 12504
#define SLOTS (NSUB*BCAP)      // 2048 int2 slots per range region
#define EMAX 1791              // sorted-edge capacity (slots before tail header)
#define TAILI (EMAX*2)         // int index of 513-int offset header in region
#define K1BLKS 1563            // k1 blocks (4 waves x 8 nodes = 32 nodes/block)
#define APPBLKS (NEDGE/256)    // 8192 append blocks

typedef __attribute__((ext_vector_type(8))) short bf16x8;
typedef __attribute__((ext_vector_type(4))) short bf16x4;
typedef __attribute__((ext_vector_type(4))) float f32x4;
typedef __attribute__((ext_vector_type(2))) int   i32x2;
typedef __attribute__((ext_vector_type(2))) unsigned u32x2;

// round-half-up f32->bf16 pair pack: 2 v_add + 1 v_perm. <=0.5 ulp, unbiased.
__device__ __forceinline__ unsigned pack2bf(float a, float b) {
    unsigned ua = __float_as_uint(a) + 0x8000u;
    unsigned ub = __float_as_uint(b) + 0x8000u;
    return __builtin_amdgcn_perm(ub, ua, 0x07060302u);
}
__device__ __forceinline__ unsigned short f2bf_rhu(float a) {
    return (unsigned short)((__float_as_uint(a) + 0x8000u) >> 16);
}
__device__ __forceinline__ float lo16f(unsigned u) { return __uint_as_float(u << 16); }
__device__ __forceinline__ float hi16f(unsigned u) { return __uint_as_float(u & 0xFFFF0000u); }

union U8 { unsigned u[4]; bf16x8 v; };
union U4 { unsigned u[2]; bf16x4 v; };

// K=16 bf16 MFMA. A: lane holds A[m=lane&15][k=(lane>>4)*4+j];
// B: B[k=(lane>>4)*4+j][n=lane&15]; C/D: row=(lane>>4)*4+reg, col=lane&15.
__device__ __forceinline__ f32x4 mfma16x16x16bf16(bf16x4 a, bf16x4 b, f32x4 c) {
#if __has_builtin(__builtin_amdgcn_mfma_f32_16x16x16bf16_1k)
    return __builtin_amdgcn_mfma_f32_16x16x16bf16_1k(a, b, c, 0, 0, 0);
#elif __has_builtin(__builtin_amdgcn_mfma_f32_16x16x16_bf16)
    return __builtin_amdgcn_mfma_f32_16x16x16_bf16(a, b, c, 0, 0, 0);
#else
    f32x4 d;
    asm volatile("v_mfma_f32_16x16x16_bf16 %0, %1, %2, %3\n\ts_nop 7\n\ts_nop 7"
                 : "=&v"(d) : "v"(a), "v"(b), "v"(c));
    return d;
#endif
}

// ---------------------------------------------------------------------------
// Fused dispatch. k1 branch restructured for load coalescing:
//   step1 per fi-tile c: XtT[c] = X^T_tile @ M^T  (one K=16 MFMA)
//     A-frag: lane(j) = x[s=grp*4+j][node][c*16+col] -> per load instruction the
//     16 col-lanes are 64B-contiguous (4 transactions/instr vs r14's ~32).
//   XtT's C-layout (lane&15=k, grp*4+reg=fi) IS the A-frag of step2 -> no
//   transpose. step2: Y[k][fo] = sum_c XtT_c-asA @ W_c  (16 MFMAs).
// 8 nodes/wave, 1-node-ahead prefetch of the 16 scalars.
// ---------------------------------------------------------------------------
__global__ __launch_bounds__(256) void k1_append(
    const float* __restrict__ x, const float* __restrict__ M,
    const float* __restrict__ W, unsigned short* __restrict__ Yt,
    const int* __restrict__ rows, const int* __restrict__ cols,
    const float* __restrict__ vals, int* __restrict__ bcnt,
    i32x2* __restrict__ btmp)
{
    if (blockIdx.x < K1BLKS) {
        // ================= k1: mix (M@X) then proj (@W) =================
        const int tid  = threadIdx.x;
        const int wid  = tid >> 6;
        const int lane = tid & 63;
        const int col  = lane & 15;   // MFMA m/n index
        const int grp  = lane >> 4;   // MFMA k-group

        // W as B-frags for step2 (K=16 chunks): bw[c][t][j] = W[c*16+grp*4+j][t*16+col]
        bf16x4 bw[4][4];
#pragma unroll
        for (int c = 0; c < 4; ++c)
#pragma unroll
            for (int t = 0; t < 4; ++t) {
                U4 w4;
                w4.u[0] = pack2bf(W[(c*16 + grp*4 + 0)*FF + t*16 + col],
                                  W[(c*16 + grp*4 + 1)*FF + t*16 + col]);
                w4.u[1] = pack2bf(W[(c*16 + grp*4 + 2)*FF + t*16 + col],
                                  W[(c*16 + grp*4 + 3)*FF + t*16 + col]);
                bw[c][t] = w4.v;
            }

        // M^T as B-frag for step1: mf[j] = M[col][grp*4+j] = M^T[s][k=col]
        U4 m4;
        m4.u[0] = pack2bf(M[col*16 + grp*4 + 0], M[col*16 + grp*4 + 1]);
        m4.u[1] = pack2bf(M[col*16 + grp*4 + 2], M[col*16 + grp*4 + 3]);
        const bf16x4 mf = m4.v;

        const f32x4 zero = {0.f, 0.f, 0.f, 0.f};
        const int base_node = (blockIdx.x*4 + wid)*8;   // 6252 waves x 8 nodes

        // prefetchable 16-scalar x load: nx[c][j] = x[grp*4+j][node][c*16+col]
        // (per instruction: 16 col-lanes x 4B contiguous per grp-region)
        f32x4 cur[4], nxt[4];
#define LOADX(nd, dst)                                                        \
        {                                                                     \
            const int ndc = (nd) < NN ? (nd) : NN - 1;                        \
            _Pragma("unroll")                                                 \
            for (int c = 0; c < 4; ++c) {                                     \
                _Pragma("unroll")                                             \
                for (int j = 0; j < 4; ++j)                                   \
                    dst[c][j] = x[(size_t)(grp*4 + j)*NN*FF                   \
                                  + (size_t)ndc*FF + c*16 + col];             \
            }                                                                 \
        }

        LOADX(base_node, cur)
#pragma unroll
        for (int it = 0; it < 8; ++it) {
            const int node = base_node + it;
            if (it < 7) LOADX(node + 1, nxt)

            // step1: XtT[c] = X^T_c @ M^T   (lane&15=k, grp*4+reg=fi_local)
            f32x4 xtT[4];
#pragma unroll
            for (int c = 0; c < 4; ++c) {
                U4 xa;
                xa.u[0] = pack2bf(cur[c][0], cur[c][1]);
                xa.u[1] = pack2bf(cur[c][2], cur[c][3]);
                xtT[c] = mfma16x16x16bf16(xa.v, mf, zero);
            }

            // step2: Y[k][fo] = sum_c XtT_c-asA @ W_c
            f32x4 acc[4];
#pragma unroll
            for (int t = 0; t < 4; ++t) acc[t] = zero;
#pragma unroll
            for (int c = 0; c < 4; ++c) {
                U4 a4;
                a4.u[0] = pack2bf(xtT[c][0], xtT[c][1]);
                a4.u[1] = pack2bf(xtT[c][2], xtT[c][3]);
#pragma unroll
                for (int t = 0; t < 4; ++t)
                    acc[t] = mfma16x16x16bf16(a4.v, bw[c][t], acc[t]);
            }

            // store: acc[t] row=grp*4+reg = k, col-lane = fo_local
            if (node < NN) {
#pragma unroll
                for (int t = 0; t < 4; ++t)
#pragma unroll
                    for (int r = 0; r < 4; ++r)
                        Yt[(size_t)node*1024 + (grp*4 + r)*64 + t*16 + col] =
                            f2bf_rhu(acc[t][r]);
            }
#pragma unroll
            for (int c = 0; c < 4; ++c) cur[c] = nxt[c];
        }
#undef LOADX
    } else {
        // ================= append =================
        const int i = (blockIdx.x - K1BLKS)*256 + threadIdx.x;   // 0..NEDGE-1
        const int r = __builtin_nontemporal_load(rows + i);
        const int j = i >> 17;                        // EE = 2^17
        const int b = (r >> 5)*NSUB + (blockIdx.x & 7);
        const int pos = atomicAdd(&bcnt[b], 1);
        if (pos < BCAP) {
            i32x2 e;
            e[0] = __builtin_nontemporal_load(cols + i) | (((r & 31)*16 + j) << 16);
            e[1] = __float_as_int(__builtin_nontemporal_load(vals + i));
            btmp[(size_t)b*BCAP + pos] = e;
        }
    }
}

// ---------------------------------------------------------------------------
// sort: block per range. Counting-sort the range's edges in LDS, write back
// IN PLACE (linear, coalesced), sorted by key=(rl,j), + 513-int offset header.
// ---------------------------------------------------------------------------
__global__ __launch_bounds__(256) void sort_kernel(
    const int* __restrict__ bcnt, i32x2* __restrict__ btmp)
{
    __shared__ i32x2 sbuf[SLOTS];     // 16KB
    __shared__ int scnt[512], soff[512], scur[512], pscan[256];

    const int tid = threadIdx.x;
    const int blk = blockIdx.x;
    i32x2* region = btmp + (size_t)blk*SLOTS;

    scnt[tid] = 0; scnt[tid + 256] = 0;
    __syncthreads();

    int bc[NSUB]; i32x2 ent[NSUB];
#pragma unroll
    for (int s = 0; s < NSUB; ++s) {
        int c = bcnt[blk*NSUB + s];
        bc[s] = c < BCAP ? c : BCAP;
    }
#pragma unroll
    for (int s = 0; s < NSUB; ++s)
        if (tid < bc[s]) {
            ent[s] = region[s*BCAP + tid];
            atomicAdd(&scnt[((unsigned)ent[s][0]) >> 16], 1);
        }
    __syncthreads();

    const int a0 = scnt[2*tid], a1 = scnt[2*tid + 1];
    const int ps = a0 + a1;
    pscan[tid] = ps;
    __syncthreads();
    for (int o = 1; o < 256; o <<= 1) {
        int v = (tid >= o) ? pscan[tid - o] : 0;
        __syncthreads();
        pscan[tid] += v;
        __syncthreads();
    }
    const int excl = pscan[tid] - ps;
    soff[2*tid] = excl;      soff[2*tid + 1] = excl + a0;
    scur[2*tid] = excl;      scur[2*tid + 1] = excl + a0;
    __syncthreads();

#pragma unroll
    for (int s = 0; s < NSUB; ++s)
        if (tid < bc[s]) {
            const int key = ((unsigned)ent[s][0]) >> 16;
            const int pos = atomicAdd(&scur[key], 1);
            i32x2 se; se[0] = ent[s][0] & 0xFFFF; se[1] = ent[s][1];
            sbuf[pos] = se;
        }
    __syncthreads();

    const int total = soff[511] + scnt[511];
    const int lim = total < EMAX ? total : EMAX;
    for (int i = tid; i < lim; i += 256) region[i] = sbuf[i];
    int* tail = (int*)region + TAILI;
    tail[tid] = soff[tid];
    tail[tid + 256] = soff[tid + 256];
    if (tid == 0) tail[512] = lim;
}

// ---------------------------------------------------------------------------
// k2_gather: one wave per row (proven ~154us). acc[16], plain loads.
// Cache effectiveness (L3 on the Yt gather stream), not occupancy, binds here
// (r10/r11 evidence). Unchanged.
// ---------------------------------------------------------------------------
template<int J>
__device__ __forceinline__ void k2_batch(int p0, int nj, int sbase, int esub, int fq,
    const i32x2* eb, const unsigned short* __restrict__ Yt,
    const float* __restrict__ M, f32x4* acc)
{
    const int p = p0 + esub;
    const bool act = p < nj;
    const int li = act ? (sbase + p) : 0;
    const i32x2 ent = eb[li];                 // LDS read
    const float v = act ? __int_as_float(ent[1]) : 0.f;
    const int node = act ? ent[0] : 0;        // masked lanes read Yt[0]
    const unsigned short* yb = Yt + (size_t)node*1024 + J*64 + fq*4;
    {
        const u32x2 uv = *reinterpret_cast<const u32x2*>(yb);
        const float wv = M[J*17] * v;
        acc[J][0] = fmaf(wv, lo16f(uv[0]), acc[J][0]);
        acc[J][1] = fmaf(wv, hi16f(uv[0]), acc[J][1]);
        acc[J][2] = fmaf(wv, lo16f(uv[1]), acc[J][2]);
        acc[J][3] = fmaf(wv, hi16f(uv[1]), acc[J][3]);
    }
    if constexpr (J < 15) {
        const u32x2 uv = *reinterpret_cast<const u32x2*>(yb + 64);
        const float wv = M[J*17 + 16] * v;
        acc[J+1][0] = fmaf(wv, lo16f(uv[0]), acc[J+1][0]);
        acc[J+1][1] = fmaf(wv, hi16f(uv[0]), acc[J+1][1]);
        acc[J+1][2] = fmaf(wv, lo16f(uv[1]), acc[J+1][2]);
        acc[J+1][3] = fmaf(wv, hi16f(uv[1]), acc[J+1][3]);
    }
    if constexpr (J < 14) {
        const u32x2 uv = *reinterpret_cast<const u32x2*>(yb + 128);
        const float wv = M[J*17 + 32] * v;
        acc[J+2][0] = fmaf(wv, lo16f(uv[0]), acc[J+2][0]);
        acc[J+2][1] = fmaf(wv, hi16f(uv[0]), acc[J+2][1]);
        acc[J+2][2] = fmaf(wv, lo16f(uv[1]), acc[J+2][2]);
        acc[J+2][3] = fmaf(wv, hi16f(uv[1]), acc[J+2][3]);
    }
}

__global__ __launch_bounds__(256) void k2_gather(
    const unsigned short* __restrict__ Yt, const float* __restrict__ M,
    const i32x2* __restrict__ btmp, float* __restrict__ out)
{
    __shared__ i32x2 ebuf[4][128];
    const int tid  = threadIdx.x;
    const int wid  = tid >> 6;
    const int lane = tid & 63;
    const int esub = lane >> 4;   // edge slot 0..3
    const int fq   = lane & 15;   // feature quad
    const int r   = blockIdx.x*4 + wid;   // 12500*4 = 50000 exact
    const int blk = r >> 5;
    const int rl  = r & 31;

    const i32x2* region = btmp + (size_t)blk*SLOTS;
    const int* tail = (const int*)region + TAILI;
    int o_l = 0;
    if (lane < 17) o_l = tail[rl*16 + lane];
    int off[17];
#pragma unroll
    for (int j = 0; j < 17; ++j) off[j] = __builtin_amdgcn_readlane(o_l, j);
    int ntot = off[16] - off[0];
    ntot = ntot < 128 ? ntot : 128;
    const i32x2* rowsrc = region + off[0];

    i32x2* eb = ebuf[wid];
    if (lane < ntot)      eb[lane]      = rowsrc[lane];
    if (lane + 64 < ntot) eb[lane + 64] = rowsrc[lane + 64];

    int c[16], sb[16];
#pragma unroll
    for (int j = 0; j < 16; ++j) {
        c[j]  = off[j+1] - off[j];
        sb[j] = off[j] - off[0];
    }

    f32x4 acc[16];
#pragma unroll
    for (int k = 0; k < 16; ++k) acc[k] = (f32x4){0.f, 0.f, 0.f, 0.f};

    // pass 1: first batch of every section, straight-line
#define P1(J) k2_batch<J>(0, c[J], sb[J], esub, fq, eb, Yt, M, acc);
    P1(0)  P1(1)  P1(2)  P1(3)  P1(4)  P1(5)  P1(6)  P1(7)
    P1(8)  P1(9)  P1(10) P1(11) P1(12) P1(13) P1(14) P1(15)
#undef P1
    // pass 2: residual batches (usually empty)
#define P2(J) for (int p0 = 4; p0 < c[J]; p0 += 4) \
        k2_batch<J>(p0, c[J], sb[J], esub, fq, eb, Yt, M, acc);
    P2(0)  P2(1)  P2(2)  P2(3)  P2(4)  P2(5)  P2(6)  P2(7)
    P2(8)  P2(9)  P2(10) P2(11) P2(12) P2(13) P2(14) P2(15)
#undef P2

#pragma unroll
    for (int k = 0; k < 16; ++k) {
#pragma unroll
        for (int u = 0; u < 4; ++u) {
            acc[k][u] += __shfl_xor(acc[k][u], 16);
            acc[k][u] += __shfl_xor(acc[k][u], 32);
        }
    }
    if (esub == 0) {
#pragma unroll
        for (int k = 0; k < 16; ++k) {
            *reinterpret_cast<f32x4*>(out + ((size_t)k*NN + r)*FF + fq*4) = acc[k];
        }
    }
}

// ---------------------------------------------------------------------------
extern "C" void kernel_launch(void* const* d_in, const int* in_sizes, int n_in,
                              void* d_out, int out_size, void* d_ws, size_t ws_size,
                              hipStream_t stream) {
    (void)in_sizes; (void)n_in; (void)out_size; (void)ws_size;
    const float* x     = (const float*)d_in[0];
    const float* M     = (const float*)d_in[1];
    const float* avals = (const float*)d_in[2];
    const float* W     = (const float*)d_in[3];
    const int*   arows = (const int*)d_in[4];
    const int*   acols = (const int*)d_in[5];
    float* out = (float*)d_out;

    // workspace carve (~128.1 MB total)
    char* ws = (char*)d_ws;
    size_t o = 0;
    unsigned short* Yt = (unsigned short*)(ws + o); o += (size_t)TT*NN*FF*2;  // 102.4 MB
    o = (o + 255) & ~(size_t)255;
    int* bcnt = (int*)(ws + o); o += (size_t)NBUCK*4;  o = (o + 255) & ~(size_t)255;
    i32x2* btmp = (i32x2*)(ws + o);                    // 12504*2048*8 = 25.6 MB

    (void)hipMemsetAsync(bcnt, 0, (size_t)NBUCK*4, stream);
    hipLaunchKernelGGL(k1_append, dim3(K1BLKS + APPBLKS), dim3(256), 0, stream,
                       x, M, W, Yt, arows, acols, avals, bcnt, btmp);
    hipLaunchKernelGGL(sort_kernel, dim3(NRANGE), dim3(256), 0, stream, bcnt, btmp);
    hipLaunchKernelGGL(k2_gather, dim3(12500), dim3(256), 0, stream, Yt, M, btmp, out);
}